// Round 8
// baseline (287.808 us; speedup 1.0000x reference)
//
#include <hip/hip_runtime.h>
#include <hip/hip_bf16.h>

// B=2, C=8, L=1024, H=512
// out[((b*1024+l)*1024+m)*8 + c] = a[b,c,l] + bb[b,c,m] + sum_h start*v4*end
//
// Round 8 = round 7 resubmitted (infra failure, never measured).
// Isolation round: two-kernel structure (round-0, verified) with the ONLY
// change being c-split in gemm_k: grid 1024, one c-plane per block, acc
// halves to 64 AGPRs (register-starvation theory test). No fusion, no
// pipeline, no swizzle. sums_k byte-identical to round 0.

typedef short bf16x8 __attribute__((ext_vector_type(8)));
typedef float f32x4 __attribute__((ext_vector_type(4)));

__device__ __forceinline__ unsigned short f2bf(float x) {
    unsigned int u = __float_as_uint(x);
    u += 0x7fffu + ((u >> 16) & 1u);   // round-to-nearest-even
    return (unsigned short)(u >> 16);
}

__device__ __forceinline__ uint4 pack8(float4 a, float4 b) {
    uint4 r;
    r.x = (unsigned)f2bf(a.x) | ((unsigned)f2bf(a.y) << 16);
    r.y = (unsigned)f2bf(a.z) | ((unsigned)f2bf(a.w) << 16);
    r.z = (unsigned)f2bf(b.x) | ((unsigned)f2bf(b.y) << 16);
    r.w = (unsigned)f2bf(b.z) | ((unsigned)f2bf(b.w) << 16);
    return r;
}

// ---------------- Kernel 1: row sums (round-0 verified, unchanged) ----------------
__global__ __launch_bounds__(256) void sums_k(const float* __restrict__ sh,
                                              const float* __restrict__ eh,
                                              const float* __restrict__ v,
                                              float* __restrict__ ws) {
    const int gid  = blockIdx.x * 256 + threadIdx.x;
    const int row  = gid >> 6;
    const int lane = gid & 63;
    const int h    = lane * 8;

    const float* ps = sh + (size_t)row * 512 + h;
    const float* pe = eh + (size_t)row * 512 + h;
    float4 s0 = *(const float4*)ps;       float4 s1 = *(const float4*)(ps + 4);
    float4 e0 = *(const float4*)pe;       float4 e1 = *(const float4*)(pe + 4);
    float4 v10 = *(const float4*)(v + h);        float4 v11 = *(const float4*)(v + h + 4);
    float4 v20 = *(const float4*)(v + 512 + h);  float4 v21 = *(const float4*)(v + 512 + h + 4);
    float4 v30 = *(const float4*)(v + 1024 + h); float4 v31 = *(const float4*)(v + 1024 + h + 4);

    float da = s0.x*(v10.x+v30.x) + s0.y*(v10.y+v30.y) + s0.z*(v10.z+v30.z) + s0.w*(v10.w+v30.w)
             + s1.x*(v11.x+v31.x) + s1.y*(v11.y+v31.y) + s1.z*(v11.z+v31.z) + s1.w*(v11.w+v31.w);
    float db = e0.x*(v20.x-v30.x) + e0.y*(v20.y-v30.y) + e0.z*(v20.z-v30.z) + e0.w*(v20.w-v30.w)
             + e1.x*(v21.x-v31.x) + e1.y*(v21.y-v31.y) + e1.z*(v21.z-v31.z) + e1.w*(v21.w-v31.w);

    #pragma unroll
    for (int off = 32; off >= 1; off >>= 1) {
        da += __shfl_down(da, off, 64);
        db += __shfl_down(db, off, 64);
    }
    if (lane == 0) {
        ws[row]         = da;
        ws[16384 + row] = db;
    }
}

// ---------------- Kernel 2: batched GEMM, c-split ----------------
// grid = 1024: bid = c*128 + (b*64 + lt*8 + mt); c in HIGH bits so the 8
// c-siblings of a tile share bid%8 (same XCD slot) for L2 write merging.
__global__ __launch_bounds__(256, 2) void gemm_k(const float* __restrict__ sh,
                                                 const float* __restrict__ eh,
                                                 const float* __restrict__ v,
                                                 const float* __restrict__ ws,
                                                 float* __restrict__ out) {
    // LDS: [row 0..127][k 0..31 (+8 pad)] bf16 (10 KB each, round-0 layout minus c2)
    __shared__ __align__(16) unsigned short As[128 * 40];
    __shared__ __align__(16) unsigned short Bs[128 * 40];

    const int t    = threadIdx.x;
    const int bid  = blockIdx.x;
    const int c    = bid >> 7;
    const int rem  = bid & 127;
    const int b    = rem >> 6;
    const int lt   = (rem >> 3) & 7;
    const int mt   = rem & 7;
    const int lbase = lt * 128, mbase = mt * 128;

    const int lane = t & 63, wave = t >> 6;
    const int ln15 = lane & 15, quad = lane >> 4;
    const int wl   = wave >> 1, wm = wave & 1;

    const int k8   = t & 3;       // fixed k-subblock per thread
    const int lrow = t >> 2;      // 0..63

    const float* baseA = sh + ((size_t)(b * 8 + c)) * 1024 * 512;
    const float* baseB = eh + ((size_t)(b * 8 + c)) * 1024 * 512;

    f32x4 acc[4][4] = {};

    for (int ks = 0; ks < 16; ++ks) {
        const int k0 = ks * 32 + k8 * 8;
        // v4 weights for this thread's fixed k-slice (round-0 path: global reads)
        float4 w0 = *(const float4*)(v + 1536 + k0);
        float4 w1 = *(const float4*)(v + 1536 + k0 + 4);

        // rows lrow and lrow+64 of the 128-row tile (2 A rows + 2 B rows)
        const float* pa0 = baseA + (size_t)(lbase + lrow) * 512 + k0;
        const float* pa1 = baseA + (size_t)(lbase + 64 + lrow) * 512 + k0;
        const float* pb0 = baseB + (size_t)(mbase + lrow) * 512 + k0;
        const float* pb1 = baseB + (size_t)(mbase + 64 + lrow) * 512 + k0;
        float4 a00 = *(const float4*)pa0;  float4 a01 = *(const float4*)(pa0 + 4);
        float4 a10 = *(const float4*)pa1;  float4 a11 = *(const float4*)(pa1 + 4);
        float4 b00 = *(const float4*)pb0;  float4 b01 = *(const float4*)(pb0 + 4);
        float4 b10 = *(const float4*)pb1;  float4 b11 = *(const float4*)(pb1 + 4);

        __syncthreads();   // previous iter's LDS reads done

        // v4 folded into A side (round-0 scheme)
        a00.x *= w0.x; a00.y *= w0.y; a00.z *= w0.z; a00.w *= w0.w;
        a01.x *= w1.x; a01.y *= w1.y; a01.z *= w1.z; a01.w *= w1.w;
        a10.x *= w0.x; a10.y *= w0.y; a10.z *= w0.z; a10.w *= w0.w;
        a11.x *= w1.x; a11.y *= w1.y; a11.z *= w1.z; a11.w *= w1.w;

        *(uint4*)&As[(lrow) * 40 + k8 * 8]      = pack8(a00, a01);
        *(uint4*)&As[(64 + lrow) * 40 + k8 * 8] = pack8(a10, a11);
        *(uint4*)&Bs[(lrow) * 40 + k8 * 8]      = pack8(b00, b01);
        *(uint4*)&Bs[(64 + lrow) * 40 + k8 * 8] = pack8(b10, b11);
        __syncthreads();

        bf16x8 aF[4], bF[4];
        #pragma unroll
        for (int i = 0; i < 4; ++i) {
            aF[i] = *(const bf16x8*)&As[(wl * 64 + i * 16 + ln15) * 40 + quad * 8];
            bF[i] = *(const bf16x8*)&Bs[(wm * 64 + i * 16 + ln15) * 40 + quad * 8];
        }
        #pragma unroll
        for (int i = 0; i < 4; ++i)
            #pragma unroll
            for (int j = 0; j < 4; ++j)
                acc[i][j] = __builtin_amdgcn_mfma_f32_16x16x32_bf16(
                    aF[i], bF[j], acc[i][j], 0, 0, 0);
    }

    // epilogue: add a[l] + bb[m] from ws (round-0 path), scalar store for this c
    const float* aw = ws + (size_t)(b * 8 + c) * 1024;
    const float* bw = ws + 16384 + (size_t)(b * 8 + c) * 1024;
    #pragma unroll
    for (int i = 0; i < 4; ++i)
        #pragma unroll
        for (int r = 0; r < 4; ++r) {
            const int l  = lbase + wl * 64 + i * 16 + quad * 4 + r;
            const float av = aw[l];
            #pragma unroll
            for (int j = 0; j < 4; ++j) {
                const int m = mbase + wm * 64 + j * 16 + ln15;
                out[(size_t)((b * 1024 + l) * 1024 + m) * 8 + c] =
                    acc[i][j][r] + av + bw[m];
            }
        }
}

extern "C" void kernel_launch(void* const* d_in, const int* in_sizes, int n_in,
                              void* d_out, int out_size, void* d_ws, size_t ws_size,
                              hipStream_t stream) {
    (void)in_sizes; (void)n_in; (void)out_size; (void)ws_size;
    const float* sh = (const float*)d_in[0];
    const float* eh = (const float*)d_in[1];
    const float* v  = (const float*)d_in[2];
    float* out = (float*)d_out;
    float* ws  = (float*)d_ws;   // 32768 floats = 128 KB

    sums_k<<<4096, 256, 0, stream>>>(sh, eh, v, ws);
    gemm_k<<<1024, 256, 0, stream>>>(sh, eh, v, ws, out);
}

// Round 9
// 219.802 us; speedup vs baseline: 1.3094x; 1.3094x over previous
//
#include <hip/hip_runtime.h>
#include <hip/hip_bf16.h>

// B=2, C=8, L=1024, H=512
// out[((b*1024+l)*1024+m)*8 + c] = a[b,c,l] + bb[b,c,m] + sum_h start*v4*end
//
// Round 9: write-path fix. One block owns ALL 8 c of a 64(l)x128(m) tile:
// grid 256 = b(2) x lt(16) x mt(8), block 512 = 8 waves, wave w = c-plane w.
// K-loop: verified R0 pattern (2 barriers/step, pad-40 LDS, v4 folded into A).
// Epilogue: LDS transpose to [l][m*9+c] chunks -> fully coalesced 4KB-row
// writes (every HBM write a full line). WRITE_SIZE 480MB -> ~67MB expected.
// sums_k unchanged (verified). No fusion, no pipeline.

typedef short bf16x8 __attribute__((ext_vector_type(8)));
typedef float f32x4 __attribute__((ext_vector_type(4)));

__device__ __forceinline__ unsigned short f2bf(float x) {
    unsigned int u = __float_as_uint(x);
    u += 0x7fffu + ((u >> 16) & 1u);   // round-to-nearest-even
    return (unsigned short)(u >> 16);
}

__device__ __forceinline__ uint4 pack8(float4 a, float4 b) {
    uint4 r;
    r.x = (unsigned)f2bf(a.x) | ((unsigned)f2bf(a.y) << 16);
    r.y = (unsigned)f2bf(a.z) | ((unsigned)f2bf(a.w) << 16);
    r.z = (unsigned)f2bf(b.x) | ((unsigned)f2bf(b.y) << 16);
    r.w = (unsigned)f2bf(b.z) | ((unsigned)f2bf(b.w) << 16);
    return r;
}

// ---------------- Kernel 1: row sums (round-0 verified, unchanged) ----------------
__global__ __launch_bounds__(256) void sums_k(const float* __restrict__ sh,
                                              const float* __restrict__ eh,
                                              const float* __restrict__ v,
                                              float* __restrict__ ws) {
    const int gid  = blockIdx.x * 256 + threadIdx.x;
    const int row  = gid >> 6;
    const int lane = gid & 63;
    const int h    = lane * 8;

    const float* ps = sh + (size_t)row * 512 + h;
    const float* pe = eh + (size_t)row * 512 + h;
    float4 s0 = *(const float4*)ps;       float4 s1 = *(const float4*)(ps + 4);
    float4 e0 = *(const float4*)pe;       float4 e1 = *(const float4*)(pe + 4);
    float4 v10 = *(const float4*)(v + h);        float4 v11 = *(const float4*)(v + h + 4);
    float4 v20 = *(const float4*)(v + 512 + h);  float4 v21 = *(const float4*)(v + 512 + h + 4);
    float4 v30 = *(const float4*)(v + 1024 + h); float4 v31 = *(const float4*)(v + 1024 + h + 4);

    float da = s0.x*(v10.x+v30.x) + s0.y*(v10.y+v30.y) + s0.z*(v10.z+v30.z) + s0.w*(v10.w+v30.w)
             + s1.x*(v11.x+v31.x) + s1.y*(v11.y+v31.y) + s1.z*(v11.z+v31.z) + s1.w*(v11.w+v31.w);
    float db = e0.x*(v20.x-v30.x) + e0.y*(v20.y-v30.y) + e0.z*(v20.z-v30.z) + e0.w*(v20.w-v30.w)
             + e1.x*(v21.x-v31.x) + e1.y*(v21.y-v31.y) + e1.z*(v21.z-v31.z) + e1.w*(v21.w-v31.w);

    #pragma unroll
    for (int off = 32; off >= 1; off >>= 1) {
        da += __shfl_down(da, off, 64);
        db += __shfl_down(db, off, 64);
    }
    if (lane == 0) {
        ws[row]         = da;
        ws[16384 + row] = db;
    }
}

// ---------------- Kernel 2: batched GEMM, all-8-c blocks ----------------
// grid 256: bid = b*128 + lt*8 + mt. bid%8 = mt, so blocks sharing a B-panel
// land on the same XCD slot (B-panel L2 locality).
__global__ __launch_bounds__(512) void gemm_k(const float* __restrict__ sh,
                                              const float* __restrict__ eh,
                                              const float* __restrict__ v,
                                              const float* __restrict__ ws,
                                              float* __restrict__ out) {
    // A: 8c x 64 l-rows, B: 8c x 128 m-rows, pad-40 (verified layout), bf16
    __shared__ __align__(16) unsigned short As[512 * 40];    // 40 KB
    __shared__ __align__(16) unsigned short Bs[1024 * 40];   // 80 KB (aliased by epilogue)

    const int t    = threadIdx.x;
    const int bid  = blockIdx.x;
    const int b    = bid >> 7;
    const int lt   = (bid >> 3) & 15;
    const int mt   = bid & 7;
    const int lbase = lt * 64, mbase = mt * 128;

    const int lane = t & 63, wave = t >> 6;   // wave = c-plane (0..7)
    const int ln15 = lane & 15, quad = lane >> 4;

    const int k8  = t & 3;        // k-subblock (8 floats each)
    const int rid = t >> 2;       // 0..127

    f32x4 acc[4][8] = {};         // [i: l-frag][j: m-frag], 128 f32/lane

    for (int ks = 0; ks < 16; ++ks) {
        const int k0 = ks * 32 + k8 * 8;
        float4 w0 = *(const float4*)(v + 1536 + k0);
        float4 w1 = *(const float4*)(v + 1536 + k0 + 4);

        // load this k-step's A rows (4 segs over 512 rows) and B rows (8 segs over 1024)
        float4 xa[4][2], xb[8][2];
        #pragma unroll
        for (int s = 0; s < 4; ++s) {
            const int gr = s * 128 + rid;          // 0..511 = cc*64 + arow
            const int cc = gr >> 6, arow = gr & 63;
            const float* p = sh + ((size_t)(b * 8 + cc) * 1024 + lbase + arow) * 512 + k0;
            xa[s][0] = *(const float4*)p;  xa[s][1] = *(const float4*)(p + 4);
        }
        #pragma unroll
        for (int s = 0; s < 8; ++s) {
            const int gr = s * 128 + rid;          // 0..1023 = cc*128 + brow
            const int cc = gr >> 7, brow = gr & 127;
            const float* p = eh + ((size_t)(b * 8 + cc) * 1024 + mbase + brow) * 512 + k0;
            xb[s][0] = *(const float4*)p;  xb[s][1] = *(const float4*)(p + 4);
        }

        __syncthreads();   // previous iter's LDS frag-reads done

        #pragma unroll
        for (int s = 0; s < 4; ++s) {
            const int gr = s * 128 + rid;
            float4 a0 = xa[s][0], a1 = xa[s][1];
            a0.x *= w0.x; a0.y *= w0.y; a0.z *= w0.z; a0.w *= w0.w;   // v4 on A side
            a1.x *= w1.x; a1.y *= w1.y; a1.z *= w1.z; a1.w *= w1.w;
            *(uint4*)&As[gr * 40 + k8 * 8] = pack8(a0, a1);
        }
        #pragma unroll
        for (int s = 0; s < 8; ++s) {
            const int gr = s * 128 + rid;
            *(uint4*)&Bs[gr * 40 + k8 * 8] = pack8(xb[s][0], xb[s][1]);
        }
        __syncthreads();

        bf16x8 aF[4], bF[8];
        #pragma unroll
        for (int i = 0; i < 4; ++i)
            aF[i] = *(const bf16x8*)&As[(wave * 64 + i * 16 + ln15) * 40 + quad * 8];
        #pragma unroll
        for (int j = 0; j < 8; ++j)
            bF[j] = *(const bf16x8*)&Bs[(wave * 128 + j * 16 + ln15) * 40 + quad * 8];
        #pragma unroll
        for (int i = 0; i < 4; ++i)
            #pragma unroll
            for (int j = 0; j < 8; ++j)
                acc[i][j] = __builtin_amdgcn_mfma_f32_16x16x32_bf16(
                    aF[i], bF[j], acc[i][j], 0, 0, 0);
    }

    // ---- epilogue: LDS transpose to c-contiguous, full-line writes ----
    // per wave: c = wave; l = lbase + i*16 + quad*4 + r; m = mbase + j*16 + ln15
    const float* aw = ws + (size_t)(b * 8 + wave) * 1024;
    const float* bw = ws + 16384 + (size_t)(b * 8 + wave) * 1024;
    float av[4][4], bv[8];
    #pragma unroll
    for (int i = 0; i < 4; ++i)
        #pragma unroll
        for (int r = 0; r < 4; ++r)
            av[i][r] = aw[lbase + i * 16 + quad * 4 + r];
    #pragma unroll
    for (int j = 0; j < 8; ++j)
        bv[j] = bw[mbase + j * 16 + ln15];

    float* smE = (float*)Bs;          // 20480 floats available; need 16*1153=18448
    const int RS = 1153;              // row stride (floats), odd => banks spread
    #pragma unroll
    for (int i = 0; i < 4; ++i) {     // 4 chunks of 16 l-rows
        __syncthreads();              // prior chunk reads (or K-loop reads) done
        #pragma unroll
        for (int j = 0; j < 8; ++j)
            #pragma unroll
            for (int r = 0; r < 4; ++r)
                smE[(quad * 4 + r) * RS + (j * 16 + ln15) * 9 + wave] =
                    acc[i][j][r] + av[i][r] + bv[j];
        __syncthreads();
        // readout: wave handles chunk-rows {wave, 8+wave}; per lane 16 floats
        #pragma unroll
        for (int rr = 0; rr < 2; ++rr) {
            const int lr = rr * 8 + wave;
            const int l  = lbase + i * 16 + lr;
            const int e0 = lr * RS + (2 * lane) * 9;
            const int e1 = e0 + 9;
            float4 o0, o1, o2, o3;
            o0.x = smE[e0 + 0]; o0.y = smE[e0 + 1]; o0.z = smE[e0 + 2]; o0.w = smE[e0 + 3];
            o1.x = smE[e0 + 4]; o1.y = smE[e0 + 5]; o1.z = smE[e0 + 6]; o1.w = smE[e0 + 7];
            o2.x = smE[e1 + 0]; o2.y = smE[e1 + 1]; o2.z = smE[e1 + 2]; o2.w = smE[e1 + 3];
            o3.x = smE[e1 + 4]; o3.y = smE[e1 + 5]; o3.z = smE[e1 + 6]; o3.w = smE[e1 + 7];
            float* po = out + ((size_t)(b * 1024 + l) * 1024 + mbase) * 8 + lane * 16;
            *(float4*)(po)      = o0;
            *(float4*)(po + 4)  = o1;
            *(float4*)(po + 8)  = o2;
            *(float4*)(po + 12) = o3;
        }
    }
}

extern "C" void kernel_launch(void* const* d_in, const int* in_sizes, int n_in,
                              void* d_out, int out_size, void* d_ws, size_t ws_size,
                              hipStream_t stream) {
    (void)in_sizes; (void)n_in; (void)out_size; (void)ws_size;
    const float* sh = (const float*)d_in[0];
    const float* eh = (const float*)d_in[1];
    const float* v  = (const float*)d_in[2];
    float* out = (float*)d_out;
    float* ws  = (float*)d_ws;   // 32768 floats = 128 KB

    sums_k<<<4096, 256, 0, stream>>>(sh, eh, v, ws);
    gemm_k<<<256, 512, 0, stream>>>(sh, eh, v, ws, out);
}

// Round 10
// 211.844 us; speedup vs baseline: 1.3586x; 1.0376x over previous
//
#include <hip/hip_runtime.h>
#include <hip/hip_bf16.h>

// B=2, C=8, L=1024, H=512
// out[((b*1024+l)*1024+m)*8 + c] = a[b,c,l] + bb[b,c,m] + sum_h start*v4*end
//
// Round 10: barrier-free K-loop. Each wave owns c-plane wave (64l x 128m) and
// stages its OWN A/B rows into a PRIVATE LDS region (192 rows x pad-40, 15KB;
// 8 waves = 120KB). No __syncthreads in the K-loop: all ordering is intra-wave
// (compiler lgkmcnt/vmcnt). Waves drift -> memory latency hidden by TLP.
// Per-wave math identical to round-9 (verified). Round-9 transpose epilogue
// kept verbatim (chunk barriers re-sync). sums_k unchanged (verified).

typedef short bf16x8 __attribute__((ext_vector_type(8)));
typedef float f32x4 __attribute__((ext_vector_type(4)));

__device__ __forceinline__ unsigned short f2bf(float x) {
    unsigned int u = __float_as_uint(x);
    u += 0x7fffu + ((u >> 16) & 1u);   // round-to-nearest-even
    return (unsigned short)(u >> 16);
}

__device__ __forceinline__ uint4 pack8(float4 a, float4 b) {
    uint4 r;
    r.x = (unsigned)f2bf(a.x) | ((unsigned)f2bf(a.y) << 16);
    r.y = (unsigned)f2bf(a.z) | ((unsigned)f2bf(a.w) << 16);
    r.z = (unsigned)f2bf(b.x) | ((unsigned)f2bf(b.y) << 16);
    r.w = (unsigned)f2bf(b.z) | ((unsigned)f2bf(b.w) << 16);
    return r;
}

// ---------------- Kernel 1: row sums (round-0 verified, unchanged) ----------------
__global__ __launch_bounds__(256) void sums_k(const float* __restrict__ sh,
                                              const float* __restrict__ eh,
                                              const float* __restrict__ v,
                                              float* __restrict__ ws) {
    const int gid  = blockIdx.x * 256 + threadIdx.x;
    const int row  = gid >> 6;
    const int lane = gid & 63;
    const int h    = lane * 8;

    const float* ps = sh + (size_t)row * 512 + h;
    const float* pe = eh + (size_t)row * 512 + h;
    float4 s0 = *(const float4*)ps;       float4 s1 = *(const float4*)(ps + 4);
    float4 e0 = *(const float4*)pe;       float4 e1 = *(const float4*)(pe + 4);
    float4 v10 = *(const float4*)(v + h);        float4 v11 = *(const float4*)(v + h + 4);
    float4 v20 = *(const float4*)(v + 512 + h);  float4 v21 = *(const float4*)(v + 512 + h + 4);
    float4 v30 = *(const float4*)(v + 1024 + h); float4 v31 = *(const float4*)(v + 1024 + h + 4);

    float da = s0.x*(v10.x+v30.x) + s0.y*(v10.y+v30.y) + s0.z*(v10.z+v30.z) + s0.w*(v10.w+v30.w)
             + s1.x*(v11.x+v31.x) + s1.y*(v11.y+v31.y) + s1.z*(v11.z+v31.z) + s1.w*(v11.w+v31.w);
    float db = e0.x*(v20.x-v30.x) + e0.y*(v20.y-v30.y) + e0.z*(v20.z-v30.z) + e0.w*(v20.w-v30.w)
             + e1.x*(v21.x-v31.x) + e1.y*(v21.y-v31.y) + e1.z*(v21.z-v31.z) + e1.w*(v21.w-v31.w);

    #pragma unroll
    for (int off = 32; off >= 1; off >>= 1) {
        da += __shfl_down(da, off, 64);
        db += __shfl_down(db, off, 64);
    }
    if (lane == 0) {
        ws[row]         = da;
        ws[16384 + row] = db;
    }
}

// ---------------- Kernel 2: batched GEMM, per-wave private staging ----------------
// grid 256: bid = b*128 + lt*8 + mt. bid%8 = mt, so blocks sharing a B-panel
// land on the same XCD slot (B-panel L2 locality).
__global__ __launch_bounds__(512, 2) void gemm_k(const float* __restrict__ sh,
                                                 const float* __restrict__ eh,
                                                 const float* __restrict__ v,
                                                 const float* __restrict__ ws,
                                                 float* __restrict__ out) {
    // per-wave region: rows [wave*192 .. wave*192+191]; A rows 0..63, B rows 64..191
    // pad-40 shorts per row. 8 x 192 x 40 x 2B = 120 KB.
    __shared__ __align__(16) unsigned short smem[8 * 192 * 40];

    const int t    = threadIdx.x;
    const int bid  = blockIdx.x;
    const int b    = bid >> 7;
    const int lt   = (bid >> 3) & 15;
    const int mt   = bid & 7;
    const int lbase = lt * 64, mbase = mt * 128;

    const int lane = t & 63, wave = t >> 6;   // wave = c-plane (0..7)
    const int ln15 = lane & 15, quad = lane >> 4;

    const int k8 = lane & 3;      // k-subblock (8 floats) within 32-k step
    const int rr = lane >> 2;     // 0..15: row-group within the wave's tile

    const int wb = wave * 192;    // this wave's LDS row base

    // this wave's global row bases (c = wave)
    const float* baseA = sh + ((size_t)(b * 8 + wave) * 1024 + lbase) * 512;
    const float* baseB = eh + ((size_t)(b * 8 + wave) * 1024 + mbase) * 512;

    f32x4 acc[4][8] = {};         // [i: l-frag][j: m-frag], 128 f32/lane

    for (int ks = 0; ks < 16; ++ks) {
        const int k0 = ks * 32 + k8 * 8;
        float4 w0 = *(const float4*)(v + 1536 + k0);
        float4 w1 = *(const float4*)(v + 1536 + k0 + 4);

        // load this wave's A rows (4 segs over 64) and B rows (8 segs over 128)
        float4 xa[4][2], xb[8][2];
        #pragma unroll
        for (int s = 0; s < 4; ++s) {
            const float* p = baseA + (size_t)(s * 16 + rr) * 512 + k0;
            xa[s][0] = *(const float4*)p;  xa[s][1] = *(const float4*)(p + 4);
        }
        #pragma unroll
        for (int s = 0; s < 8; ++s) {
            const float* p = baseB + (size_t)(s * 16 + rr) * 512 + k0;
            xb[s][0] = *(const float4*)p;  xb[s][1] = *(const float4*)(p + 4);
        }

        // pack -> this wave's private LDS (no barrier; intra-wave ordering only)
        #pragma unroll
        for (int s = 0; s < 4; ++s) {
            float4 a0 = xa[s][0], a1 = xa[s][1];
            a0.x *= w0.x; a0.y *= w0.y; a0.z *= w0.z; a0.w *= w0.w;   // v4 on A side
            a1.x *= w1.x; a1.y *= w1.y; a1.z *= w1.z; a1.w *= w1.w;
            *(uint4*)&smem[(wb + s * 16 + rr) * 40 + k8 * 8] = pack8(a0, a1);
        }
        #pragma unroll
        for (int s = 0; s < 8; ++s)
            *(uint4*)&smem[(wb + 64 + s * 16 + rr) * 40 + k8 * 8] = pack8(xb[s][0], xb[s][1]);

        bf16x8 aF[4], bF[8];
        #pragma unroll
        for (int i = 0; i < 4; ++i)
            aF[i] = *(const bf16x8*)&smem[(wb + i * 16 + ln15) * 40 + quad * 8];
        #pragma unroll
        for (int j = 0; j < 8; ++j)
            bF[j] = *(const bf16x8*)&smem[(wb + 64 + j * 16 + ln15) * 40 + quad * 8];
        #pragma unroll
        for (int i = 0; i < 4; ++i)
            #pragma unroll
            for (int j = 0; j < 8; ++j)
                acc[i][j] = __builtin_amdgcn_mfma_f32_16x16x32_bf16(
                    aF[i], bF[j], acc[i][j], 0, 0, 0);
    }

    // ---- epilogue: LDS transpose to c-contiguous, full-line writes (R9 verified) ----
    const float* aw = ws + (size_t)(b * 8 + wave) * 1024;
    const float* bw = ws + 16384 + (size_t)(b * 8 + wave) * 1024;
    float av[4][4], bv[8];
    #pragma unroll
    for (int i = 0; i < 4; ++i)
        #pragma unroll
        for (int r = 0; r < 4; ++r)
            av[i][r] = aw[lbase + i * 16 + quad * 4 + r];
    #pragma unroll
    for (int j = 0; j < 8; ++j)
        bv[j] = bw[mbase + j * 16 + ln15];

    float* smE = (float*)smem;        // 30720 floats available; need 16*1153=18448
    const int RS = 1153;              // row stride (floats), odd => banks spread
    #pragma unroll
    for (int i = 0; i < 4; ++i) {     // 4 chunks of 16 l-rows
        __syncthreads();              // K-loop reads (chunk 0) / prior chunk reads done
        #pragma unroll
        for (int j = 0; j < 8; ++j)
            #pragma unroll
            for (int r = 0; r < 4; ++r)
                smE[(quad * 4 + r) * RS + (j * 16 + ln15) * 9 + wave] =
                    acc[i][j][r] + av[i][r] + bv[j];
        __syncthreads();
        // readout: wave handles chunk-rows {wave, 8+wave}; per lane 16 floats
        #pragma unroll
        for (int rr2 = 0; rr2 < 2; ++rr2) {
            const int lr = rr2 * 8 + wave;
            const int l  = lbase + i * 16 + lr;
            const int e0 = lr * RS + (2 * lane) * 9;
            const int e1 = e0 + 9;
            float4 o0, o1, o2, o3;
            o0.x = smE[e0 + 0]; o0.y = smE[e0 + 1]; o0.z = smE[e0 + 2]; o0.w = smE[e0 + 3];
            o1.x = smE[e0 + 4]; o1.y = smE[e0 + 5]; o1.z = smE[e0 + 6]; o1.w = smE[e0 + 7];
            o2.x = smE[e1 + 0]; o2.y = smE[e1 + 1]; o2.z = smE[e1 + 2]; o2.w = smE[e1 + 3];
            o3.x = smE[e1 + 4]; o3.y = smE[e1 + 5]; o3.z = smE[e1 + 6]; o3.w = smE[e1 + 7];
            float* po = out + ((size_t)(b * 1024 + l) * 1024 + mbase) * 8 + lane * 16;
            *(float4*)(po)      = o0;
            *(float4*)(po + 4)  = o1;
            *(float4*)(po + 8)  = o2;
            *(float4*)(po + 12) = o3;
        }
    }
}

extern "C" void kernel_launch(void* const* d_in, const int* in_sizes, int n_in,
                              void* d_out, int out_size, void* d_ws, size_t ws_size,
                              hipStream_t stream) {
    (void)in_sizes; (void)n_in; (void)out_size; (void)ws_size;
    const float* sh = (const float*)d_in[0];
    const float* eh = (const float*)d_in[1];
    const float* v  = (const float*)d_in[2];
    float* out = (float*)d_out;
    float* ws  = (float*)d_ws;   // 32768 floats = 128 KB

    sums_k<<<4096, 256, 0, stream>>>(sh, eh, v, ws);
    gemm_k<<<256, 512, 0, stream>>>(sh, eh, v, ws, out);
}

// Round 11
// 170.561 us; speedup vs baseline: 1.6874x; 1.2420x over previous
//
#include <hip/hip_runtime.h>
#include <hip/hip_bf16.h>

// B=2, C=8, L=1024, H=512
// out[((b*1024+l)*1024+m)*8 + c] = a[b,c,l] + bb[b,c,m] + sum_h start*v4*end
//
// Round 11: traffic reduction. Theory: all rounds 0-10 are bound at ~4 TB/s of
// L2/L3-side staged-read traffic (A-panels read 8x, B-panels 16x, in f32).
// New path (needs 33.7MB workspace, guarded):
//   prep_k : read inputs once -> row dots (sums_k verbatim) + bf16 copies
//            (v4 folded into A with the same pack8 rounding).
//   gemm2_k: 32l x 256m x 8c tile, c-plane per wave, per-wave private LDS,
//            global_load_lds width-16 staging (m97 pattern), source-side XOR
//            swizzle, no K-loop barriers, near-zero VALU. XCD mapping:
//            bid%8 = b*4+mt so B-panel users share one XCD's L2.
// Fallback path (ws too small): round-10 verified kernels unchanged.

typedef short bf16x8 __attribute__((ext_vector_type(8)));
typedef float f32x4 __attribute__((ext_vector_type(4)));

__device__ __forceinline__ unsigned short f2bf(float x) {
    unsigned int u = __float_as_uint(x);
    u += 0x7fffu + ((u >> 16) & 1u);   // round-to-nearest-even
    return (unsigned short)(u >> 16);
}

__device__ __forceinline__ uint4 pack8(float4 a, float4 b) {
    uint4 r;
    r.x = (unsigned)f2bf(a.x) | ((unsigned)f2bf(a.y) << 16);
    r.y = (unsigned)f2bf(a.z) | ((unsigned)f2bf(a.w) << 16);
    r.z = (unsigned)f2bf(b.x) | ((unsigned)f2bf(b.y) << 16);
    r.w = (unsigned)f2bf(b.z) | ((unsigned)f2bf(b.w) << 16);
    return r;
}

__device__ __forceinline__ void gload16(const unsigned short* g, unsigned short* l) {
    __builtin_amdgcn_global_load_lds(
        (const __attribute__((address_space(1))) unsigned int*)g,
        (__attribute__((address_space(3))) unsigned int*)l, 16, 0, 0);
}

// ---------------- prep: row dots + bf16 conversion (one wave per row) ----------------
__global__ __launch_bounds__(256) void prep_k(const float* __restrict__ sh,
                                              const float* __restrict__ eh,
                                              const float* __restrict__ v,
                                              float* __restrict__ sums,
                                              unsigned short* __restrict__ Aw,
                                              unsigned short* __restrict__ Bw) {
    const int gid  = blockIdx.x * 256 + threadIdx.x;
    const int row  = gid >> 6;
    const int lane = gid & 63;
    const int h    = lane * 8;

    const float* ps = sh + (size_t)row * 512 + h;
    const float* pe = eh + (size_t)row * 512 + h;
    float4 s0 = *(const float4*)ps;       float4 s1 = *(const float4*)(ps + 4);
    float4 e0 = *(const float4*)pe;       float4 e1 = *(const float4*)(pe + 4);
    float4 v10 = *(const float4*)(v + h);        float4 v11 = *(const float4*)(v + h + 4);
    float4 v20 = *(const float4*)(v + 512 + h);  float4 v21 = *(const float4*)(v + 512 + h + 4);
    float4 v30 = *(const float4*)(v + 1024 + h); float4 v31 = *(const float4*)(v + 1024 + h + 4);
    float4 v40 = *(const float4*)(v + 1536 + h); float4 v41 = *(const float4*)(v + 1536 + h + 4);

    float da = s0.x*(v10.x+v30.x) + s0.y*(v10.y+v30.y) + s0.z*(v10.z+v30.z) + s0.w*(v10.w+v30.w)
             + s1.x*(v11.x+v31.x) + s1.y*(v11.y+v31.y) + s1.z*(v11.z+v31.z) + s1.w*(v11.w+v31.w);
    float db = e0.x*(v20.x-v30.x) + e0.y*(v20.y-v30.y) + e0.z*(v20.z-v30.z) + e0.w*(v20.w-v30.w)
             + e1.x*(v21.x-v31.x) + e1.y*(v21.y-v31.y) + e1.z*(v21.z-v31.z) + e1.w*(v21.w-v31.w);

    // bf16 copies: A with v4 folded (same rounding as the verified in-loop pack)
    float4 a0 = s0, a1 = s1;
    a0.x *= v40.x; a0.y *= v40.y; a0.z *= v40.z; a0.w *= v40.w;
    a1.x *= v41.x; a1.y *= v41.y; a1.z *= v41.z; a1.w *= v41.w;
    *(uint4*)&Aw[(size_t)row * 512 + h] = pack8(a0, a1);
    *(uint4*)&Bw[(size_t)row * 512 + h] = pack8(e0, e1);

    #pragma unroll
    for (int off = 32; off >= 1; off >>= 1) {
        da += __shfl_down(da, off, 64);
        db += __shfl_down(db, off, 64);
    }
    if (lane == 0) {
        sums[row]         = da;
        sums[16384 + row] = db;
    }
}

// ---------------- gemm2: bf16 GEMM, per-wave private global_load_lds staging ----------------
// grid 256: bid = lt*8 + b*4 + mt  (bid%8 = b*4+mt -> B-panel users share an XCD)
__global__ __launch_bounds__(512) void gemm2_k(const unsigned short* __restrict__ Aw,
                                               const unsigned short* __restrict__ Bw,
                                               const float* __restrict__ sums,
                                               float* __restrict__ out) {
    // per-wave region: 288 rows x 32 bf16 (64B): A rows 0..31, B rows 32..287.
    // 8 waves x 288 x 32 x 2B = 144 KB. Epilogue aliases as float scratch.
    __shared__ __align__(16) unsigned short smem[8 * 288 * 32];

    const int t    = threadIdx.x;
    const int bid  = blockIdx.x;
    const int mt   = bid & 3;
    const int b    = (bid >> 2) & 1;
    const int lt   = bid >> 3;            // 0..31
    const int lbase = lt * 32, mbase = mt * 256;

    const int lane = t & 63, wave = t >> 6;   // wave = c-plane (0..7)
    const int ln15 = lane & 15, quad = lane >> 4;

    const int rloc = lane >> 2;           // 0..15 row within a 16-row stage group
    const int slot = lane & 3;            // 16B slot within a 64B row
    const int kb   = slot ^ (rloc & 3);   // source-side XOR swizzle

    const int wb = wave * 288;            // this wave's LDS row base

    const unsigned short* baseA = Aw + ((size_t)(b * 8 + wave) * 1024 + lbase) * 512;
    const unsigned short* baseB = Bw + ((size_t)(b * 8 + wave) * 1024 + mbase) * 512;

    f32x4 acc[2][16] = {};

    for (int ks = 0; ks < 16; ++ks) {
        const unsigned short* Ag = baseA + ks * 32;
        const unsigned short* Bg = baseB + ks * 32;

        // stage A (2 insts x 16 rows) and B (16 insts) into private LDS.
        // dest is wave-uniform (base + lane*16 implicit); src is per-lane swizzled.
        #pragma unroll
        for (int s = 0; s < 2; ++s)
            gload16(Ag + (size_t)(s * 16 + rloc) * 512 + kb * 8,
                    &smem[(wb + s * 16) * 32]);
        #pragma unroll
        for (int s = 0; s < 16; ++s)
            gload16(Bg + (size_t)(s * 16 + rloc) * 512 + kb * 8,
                    &smem[(wb + 32 + s * 16) * 32]);

        asm volatile("s_waitcnt vmcnt(0)" ::: "memory");

        // frag reads: LDS[r][slot] holds global k-block slot^(r&3); invert on read.
        bf16x8 aF[2], bF[16];
        #pragma unroll
        for (int i = 0; i < 2; ++i)
            aF[i] = *(const bf16x8*)&smem[(wb + i * 16 + ln15) * 32 + ((quad ^ (ln15 & 3)) * 8)];
        #pragma unroll
        for (int j = 0; j < 16; ++j)
            bF[j] = *(const bf16x8*)&smem[(wb + 32 + j * 16 + ln15) * 32 + ((quad ^ (ln15 & 3)) * 8)];

        #pragma unroll
        for (int i = 0; i < 2; ++i)
            #pragma unroll
            for (int j = 0; j < 16; ++j)
                acc[i][j] = __builtin_amdgcn_mfma_f32_16x16x32_bf16(
                    aF[i], bF[j], acc[i][j], 0, 0, 0);
    }

    // ---- epilogue: LDS transpose to c-contiguous, full-line writes (R9/R10 verified) ----
    const float* aw = sums + (size_t)(b * 8 + wave) * 1024;
    const float* bw = sums + 16384 + (size_t)(b * 8 + wave) * 1024;
    float av[2][4];
    #pragma unroll
    for (int i = 0; i < 2; ++i)
        #pragma unroll
        for (int r = 0; r < 4; ++r)
            av[i][r] = aw[lbase + i * 16 + quad * 4 + r];
    float bv[16];
    #pragma unroll
    for (int j = 0; j < 16; ++j)
        bv[j] = bw[mbase + j * 16 + ln15];

    float* smE = (float*)smem;        // 36864 floats available; need 16*1153=18448
    const int RS = 1153;
    #pragma unroll
    for (int i = 0; i < 2; ++i)
        #pragma unroll
        for (int mh = 0; mh < 2; ++mh) {
            __syncthreads();          // K-loop reads / prior chunk reads done
            #pragma unroll
            for (int jl = 0; jl < 8; ++jl) {
                const int j = mh * 8 + jl;
                #pragma unroll
                for (int r = 0; r < 4; ++r)
                    smE[(quad * 4 + r) * RS + (jl * 16 + ln15) * 9 + wave] =
                        acc[i][j][r] + av[i][r] + bv[j];
            }
            __syncthreads();
            #pragma unroll
            for (int rr2 = 0; rr2 < 2; ++rr2) {
                const int lr = rr2 * 8 + wave;
                const int l  = lbase + i * 16 + lr;
                const int e0 = lr * RS + (2 * lane) * 9;
                const int e1 = e0 + 9;
                float4 o0, o1, o2, o3;
                o0.x = smE[e0 + 0]; o0.y = smE[e0 + 1]; o0.z = smE[e0 + 2]; o0.w = smE[e0 + 3];
                o1.x = smE[e0 + 4]; o1.y = smE[e0 + 5]; o1.z = smE[e0 + 6]; o1.w = smE[e0 + 7];
                o2.x = smE[e1 + 0]; o2.y = smE[e1 + 1]; o2.z = smE[e1 + 2]; o2.w = smE[e1 + 3];
                o3.x = smE[e1 + 4]; o3.y = smE[e1 + 5]; o3.z = smE[e1 + 6]; o3.w = smE[e1 + 7];
                float* po = out + ((size_t)(b * 1024 + l) * 1024 + mbase + mh * 128) * 8 + lane * 16;
                *(float4*)(po)      = o0;
                *(float4*)(po + 4)  = o1;
                *(float4*)(po + 8)  = o2;
                *(float4*)(po + 12) = o3;
            }
        }
}

// ======================= FALLBACK PATH (round-10 verified, unchanged) =======================
__global__ __launch_bounds__(256) void sums_k(const float* __restrict__ sh,
                                              const float* __restrict__ eh,
                                              const float* __restrict__ v,
                                              float* __restrict__ ws) {
    const int gid  = blockIdx.x * 256 + threadIdx.x;
    const int row  = gid >> 6;
    const int lane = gid & 63;
    const int h    = lane * 8;

    const float* ps = sh + (size_t)row * 512 + h;
    const float* pe = eh + (size_t)row * 512 + h;
    float4 s0 = *(const float4*)ps;       float4 s1 = *(const float4*)(ps + 4);
    float4 e0 = *(const float4*)pe;       float4 e1 = *(const float4*)(pe + 4);
    float4 v10 = *(const float4*)(v + h);        float4 v11 = *(const float4*)(v + h + 4);
    float4 v20 = *(const float4*)(v + 512 + h);  float4 v21 = *(const float4*)(v + 512 + h + 4);
    float4 v30 = *(const float4*)(v + 1024 + h); float4 v31 = *(const float4*)(v + 1024 + h + 4);

    float da = s0.x*(v10.x+v30.x) + s0.y*(v10.y+v30.y) + s0.z*(v10.z+v30.z) + s0.w*(v10.w+v30.w)
             + s1.x*(v11.x+v31.x) + s1.y*(v11.y+v31.y) + s1.z*(v11.z+v31.z) + s1.w*(v11.w+v31.w);
    float db = e0.x*(v20.x-v30.x) + e0.y*(v20.y-v30.y) + e0.z*(v20.z-v30.z) + e0.w*(v20.w-v30.w)
             + e1.x*(v21.x-v31.x) + e1.y*(v21.y-v31.y) + e1.z*(v21.z-v31.z) + e1.w*(v21.w-v31.w);

    #pragma unroll
    for (int off = 32; off >= 1; off >>= 1) {
        da += __shfl_down(da, off, 64);
        db += __shfl_down(db, off, 64);
    }
    if (lane == 0) {
        ws[row]         = da;
        ws[16384 + row] = db;
    }
}

__global__ __launch_bounds__(512, 2) void gemm_k(const float* __restrict__ sh,
                                                 const float* __restrict__ eh,
                                                 const float* __restrict__ v,
                                                 const float* __restrict__ ws,
                                                 float* __restrict__ out) {
    __shared__ __align__(16) unsigned short smem[8 * 192 * 40];

    const int t    = threadIdx.x;
    const int bid  = blockIdx.x;
    const int b    = bid >> 7;
    const int lt   = (bid >> 3) & 15;
    const int mt   = bid & 7;
    const int lbase = lt * 64, mbase = mt * 128;

    const int lane = t & 63, wave = t >> 6;
    const int ln15 = lane & 15, quad = lane >> 4;

    const int k8 = lane & 3;
    const int rr = lane >> 2;

    const int wb = wave * 192;

    const float* baseA = sh + ((size_t)(b * 8 + wave) * 1024 + lbase) * 512;
    const float* baseB = eh + ((size_t)(b * 8 + wave) * 1024 + mbase) * 512;

    f32x4 acc[4][8] = {};

    for (int ks = 0; ks < 16; ++ks) {
        const int k0 = ks * 32 + k8 * 8;
        float4 w0 = *(const float4*)(v + 1536 + k0);
        float4 w1 = *(const float4*)(v + 1536 + k0 + 4);

        float4 xa[4][2], xb[8][2];
        #pragma unroll
        for (int s = 0; s < 4; ++s) {
            const float* p = baseA + (size_t)(s * 16 + rr) * 512 + k0;
            xa[s][0] = *(const float4*)p;  xa[s][1] = *(const float4*)(p + 4);
        }
        #pragma unroll
        for (int s = 0; s < 8; ++s) {
            const float* p = baseB + (size_t)(s * 16 + rr) * 512 + k0;
            xb[s][0] = *(const float4*)p;  xb[s][1] = *(const float4*)(p + 4);
        }

        #pragma unroll
        for (int s = 0; s < 4; ++s) {
            float4 a0 = xa[s][0], a1 = xa[s][1];
            a0.x *= w0.x; a0.y *= w0.y; a0.z *= w0.z; a0.w *= w0.w;
            a1.x *= w1.x; a1.y *= w1.y; a1.z *= w1.z; a1.w *= w1.w;
            *(uint4*)&smem[(wb + s * 16 + rr) * 40 + k8 * 8] = pack8(a0, a1);
        }
        #pragma unroll
        for (int s = 0; s < 8; ++s)
            *(uint4*)&smem[(wb + 64 + s * 16 + rr) * 40 + k8 * 8] = pack8(xb[s][0], xb[s][1]);

        bf16x8 aF[4], bF[8];
        #pragma unroll
        for (int i = 0; i < 4; ++i)
            aF[i] = *(const bf16x8*)&smem[(wb + i * 16 + ln15) * 40 + quad * 8];
        #pragma unroll
        for (int j = 0; j < 8; ++j)
            bF[j] = *(const bf16x8*)&smem[(wb + 64 + j * 16 + ln15) * 40 + quad * 8];
        #pragma unroll
        for (int i = 0; i < 4; ++i)
            #pragma unroll
            for (int j = 0; j < 8; ++j)
                acc[i][j] = __builtin_amdgcn_mfma_f32_16x16x32_bf16(
                    aF[i], bF[j], acc[i][j], 0, 0, 0);
    }

    const float* aw = ws + (size_t)(b * 8 + wave) * 1024;
    const float* bw = ws + 16384 + (size_t)(b * 8 + wave) * 1024;
    float av[4][4], bv[8];
    #pragma unroll
    for (int i = 0; i < 4; ++i)
        #pragma unroll
        for (int r = 0; r < 4; ++r)
            av[i][r] = aw[lbase + i * 16 + quad * 4 + r];
    #pragma unroll
    for (int j = 0; j < 8; ++j)
        bv[j] = bw[mbase + j * 16 + ln15];

    float* smE = (float*)smem;
    const int RS = 1153;
    #pragma unroll
    for (int i = 0; i < 4; ++i) {
        __syncthreads();
        #pragma unroll
        for (int j = 0; j < 8; ++j)
            #pragma unroll
            for (int r = 0; r < 4; ++r)
                smE[(quad * 4 + r) * RS + (j * 16 + ln15) * 9 + wave] =
                    acc[i][j][r] + av[i][r] + bv[j];
        __syncthreads();
        #pragma unroll
        for (int rr2 = 0; rr2 < 2; ++rr2) {
            const int lr = rr2 * 8 + wave;
            const int l  = lbase + i * 16 + lr;
            const int e0 = lr * RS + (2 * lane) * 9;
            const int e1 = e0 + 9;
            float4 o0, o1, o2, o3;
            o0.x = smE[e0 + 0]; o0.y = smE[e0 + 1]; o0.z = smE[e0 + 2]; o0.w = smE[e0 + 3];
            o1.x = smE[e0 + 4]; o1.y = smE[e0 + 5]; o1.z = smE[e0 + 6]; o1.w = smE[e0 + 7];
            o2.x = smE[e1 + 0]; o2.y = smE[e1 + 1]; o2.z = smE[e1 + 2]; o2.w = smE[e1 + 3];
            o3.x = smE[e1 + 4]; o3.y = smE[e1 + 5]; o3.z = smE[e1 + 6]; o3.w = smE[e1 + 7];
            float* po = out + ((size_t)(b * 1024 + l) * 1024 + mbase) * 8 + lane * 16;
            *(float4*)(po)      = o0;
            *(float4*)(po + 4)  = o1;
            *(float4*)(po + 8)  = o2;
            *(float4*)(po + 12) = o3;
        }
    }
}

extern "C" void kernel_launch(void* const* d_in, const int* in_sizes, int n_in,
                              void* d_out, int out_size, void* d_ws, size_t ws_size,
                              hipStream_t stream) {
    (void)in_sizes; (void)n_in; (void)out_size;
    const float* sh = (const float*)d_in[0];
    const float* eh = (const float*)d_in[1];
    const float* v  = (const float*)d_in[2];
    float* out = (float*)d_out;

    const size_t need = 32768 * sizeof(float)
                      + 2 * (size_t)16384 * 512 * sizeof(unsigned short); // 33,685,504 B
    if (ws_size >= need) {
        float* sums = (float*)d_ws;
        unsigned short* Aw = (unsigned short*)((char*)d_ws + 32768 * sizeof(float));
        unsigned short* Bw = Aw + (size_t)16384 * 512;
        prep_k<<<4096, 256, 0, stream>>>(sh, eh, v, sums, Aw, Bw);
        gemm2_k<<<256, 512, 0, stream>>>(Aw, Bw, sums, out);
    } else {
        float* ws = (float*)d_ws;   // 32768 floats = 128 KB
        sums_k<<<4096, 256, 0, stream>>>(sh, eh, v, ws);
        gemm_k<<<256, 512, 0, stream>>>(sh, eh, v, ws, out);
    }
}